// Round 6
// baseline (2783.875 us; speedup 1.0000x reference)
//
#include <hip/hip_runtime.h>

#define D 128
#define BUNROLL 8
#define CHUNK (256 * BUNROLL)   // edges per block in hist/scatter (identical mapping!)
#define RPB 128                 // rows per bucket (LDS accumulator tile)
#define STILE 1024              // scan tile

// ---------------- relation transform (both matrices in one launch) ----------------
__global__ void transform2_kernel(const float* __restrict__ Rin, const float* __restrict__ Win,
                                  const float* __restrict__ Rout, const float* __restrict__ Wout,
                                  float* __restrict__ T_all, int nrel) {
    __shared__ float row[D];
    int b = blockIdx.x;
    bool second = (b >= nrel);
    const float* R = second ? Rout : Rin;
    const float* W = second ? Wout : Win;
    int r = second ? b - nrel : b;
    int t = threadIdx.x;
    row[t] = R[r * D + t];
    __syncthreads();
    float acc = 0.f;
#pragma unroll 8
    for (int k = 0; k < D; ++k) acc += row[k] * W[k * D + t];
    T_all[(size_t)b * D + t] = acc;
}

// ---------------- fused degree + bucket histogram ----------------
// deg_in/deg_out: f32 counts per row (for symmetric norm)
// cnt8: u32 counts per (bucket, blockgroup) where bucket=row>>7, group=blockIdx&7
__global__ __launch_bounds__(256) void hist_degree_kernel(
        const int* __restrict__ rows, int E, int E2,
        float* __restrict__ deg_in, float* __restrict__ deg_out,
        unsigned int* __restrict__ cnt8) {
    int b = blockIdx.x;
    long e0 = (long)b * CHUNK + threadIdx.x * BUNROLL;
    unsigned g = (unsigned)(b & 7);
    if (e0 + BUNROLL <= E2) {
        int r[BUNROLL];
#pragma unroll
        for (int k = 0; k < BUNROLL; ++k) r[k] = rows[e0 + k];
#pragma unroll
        for (int k = 0; k < BUNROLL; ++k) {
            float* deg = (e0 + k < E) ? deg_in : deg_out;
            atomicAdd(&deg[r[k]], 1.0f);
            atomicAdd(&cnt8[(((unsigned)r[k] >> 7) << 3) + g], 1u);
        }
    } else {
        for (int k = 0; e0 + k < E2; ++k) {
            int r = rows[e0 + k];
            float* deg = (e0 + k < E) ? deg_in : deg_out;
            atomicAdd(&deg[r], 1.0f);
            atomicAdd(&cnt8[(((unsigned)r >> 7) << 3) + g], 1u);
        }
    }
}

// deg -> deg^-1/2 in place
__global__ __launch_bounds__(256) void dinv_kernel(float* __restrict__ deg, int n) {
    int i = blockIdx.x * blockDim.x + threadIdx.x;
    int stride = gridDim.x * blockDim.x;
    for (; i < n; i += stride) {
        float d = deg[i];
        deg[i] = d > 0.f ? rsqrtf(d) : 0.f;
    }
}

// ---------------- device-wide scan over cnt8 (u32, 3 kernels) ----------------
__global__ __launch_bounds__(256) void tile_sum_u32(const unsigned int* __restrict__ cnt,
                                                    unsigned int* __restrict__ tsum, int n) {
    int tid = threadIdx.x;
    int i0 = blockIdx.x * STILE + tid * 4;
    unsigned int s = 0;
#pragma unroll
    for (int k = 0; k < 4; ++k) {
        int i = i0 + k;
        if (i < n) s += cnt[i];
    }
    __shared__ unsigned int ls[256];
    ls[tid] = s;
    __syncthreads();
    for (int off = 128; off >= 1; off >>= 1) {
        if (tid < off) ls[tid] += ls[tid + off];
        __syncthreads();
    }
    if (tid == 0) tsum[blockIdx.x] = ls[0];
}

__global__ void scan_tiles_kernel(const unsigned int* __restrict__ tile_sums,
                                  unsigned int* __restrict__ tile_off,
                                  unsigned int* __restrict__ base, int ntiles, int n) {
    int t = threadIdx.x; // blockDim = 1024
    __shared__ unsigned int ls[1024];
    unsigned int v = (t < ntiles) ? tile_sums[t] : 0u;
    ls[t] = v;
    __syncthreads();
    for (int off = 1; off < 1024; off <<= 1) {
        unsigned int add = (t >= off) ? ls[t - off] : 0u;
        __syncthreads();
        ls[t] += add;
        __syncthreads();
    }
    if (t < ntiles) tile_off[t] = ls[t] - v; // exclusive
    if (t == 1023) base[n] = ls[1023];       // grand total
}

__global__ __launch_bounds__(256) void base_write_u32(const unsigned int* __restrict__ cnt,
                                                      const unsigned int* __restrict__ tile_off,
                                                      unsigned int* __restrict__ base, int n) {
    int tid = threadIdx.x;
    int i0 = blockIdx.x * STILE + tid * 4;
    unsigned int c[4];
#pragma unroll
    for (int k = 0; k < 4; ++k) {
        int i = i0 + k;
        c[k] = (i < n) ? cnt[i] : 0u;
    }
    unsigned int s = c[0] + c[1] + c[2] + c[3];
    __shared__ unsigned int ls[256];
    ls[tid] = s;
    __syncthreads();
    for (int off = 1; off < 256; off <<= 1) {
        unsigned int add = (tid >= off) ? ls[tid - off] : 0u;
        __syncthreads();
        ls[tid] += add;
        __syncthreads();
    }
    unsigned int run = (tid > 0 ? ls[tid - 1] : 0u) + tile_off[blockIdx.x];
#pragma unroll
    for (int k = 0; k < 4; ++k) {
        int i = i0 + k;
        if (i < n) base[i] = run;
        run += c[k];
    }
}

// ---------------- scatter into XCD-affine bucket regions ----------------
// payload = (coeff_f32, row<<10 | table_row)
__global__ __launch_bounds__(256) void scatter2_kernel(
        const int* __restrict__ rows, const int* __restrict__ cols,
        const int* __restrict__ etype,
        const float* __restrict__ dinv_in, const float* __restrict__ dinv_out,
        unsigned int* __restrict__ cursor8,
        uint2* __restrict__ payload, int E, int E2, int nrel) {
    int b = blockIdx.x;
    long e0 = (long)b * CHUNK + threadIdx.x * BUNROLL;
    unsigned g = (unsigned)(b & 7);
    if (e0 + BUNROLL <= E2) {
        int r[BUNROLL], c[BUNROLL], t[BUNROLL];
#pragma unroll
        for (int k = 0; k < BUNROLL; ++k) r[k] = rows[e0 + k];
#pragma unroll
        for (int k = 0; k < BUNROLL; ++k) c[k] = cols[e0 + k];
#pragma unroll
        for (int k = 0; k < BUNROLL; ++k) t[k] = etype[e0 + k];
        float cf[BUNROLL];
#pragma unroll
        for (int k = 0; k < BUNROLL; ++k) {
            const float* dv = (e0 + k < E) ? dinv_in : dinv_out;
            cf[k] = 0.5f * dv[r[k]] * dv[c[k]];
        }
#pragma unroll
        for (int k = 0; k < BUNROLL; ++k) {
            unsigned pos = atomicAdd(&cursor8[(((unsigned)r[k] >> 7) << 3) + g], 1u);
            unsigned ty = (unsigned)(t[k] + ((e0 + k < E) ? 0 : nrel));
            payload[pos] = make_uint2(__float_as_uint(cf[k]), ((unsigned)r[k] << 10) | ty);
        }
    } else {
        for (int k = 0; e0 + k < E2; ++k) {
            long e = e0 + k;
            bool first = (e < E);
            const float* dv = first ? dinv_in : dinv_out;
            int r = rows[e];
            float cf = 0.5f * dv[r] * dv[cols[e]];
            unsigned pos = atomicAdd(&cursor8[(((unsigned)r >> 7) << 3) + g], 1u);
            payload[pos] = make_uint2(__float_as_uint(cf),
                                      ((unsigned)r << 10) | (unsigned)(etype[e] + (first ? 0 : nrel)));
        }
    }
}

// ---------------- per-bucket LDS accumulate + fused BN stats ----------------
__global__ __launch_bounds__(512) void accum2_kernel(
        const unsigned int* __restrict__ base8, const uint2* __restrict__ payload,
        const float* __restrict__ T_all, float* __restrict__ out,
        float* __restrict__ sums, float* __restrict__ sumsq, int nent) {
    __shared__ float acc[RPB * D];   // 64 KB
    __shared__ float ls[D], lq[D];
    int tid = threadIdx.x;           // 512
    int k = blockIdx.x;
    int row0 = k << 7;
    unsigned start = base8[k << 3];
    unsigned end   = base8[(k << 3) + 8];

    float4* a4 = (float4*)acc;
    for (int i = tid; i < RPB * D / 4; i += 512) a4[i] = make_float4(0.f, 0.f, 0.f, 0.f);
    if (tid < D) { ls[tid] = 0.f; lq[tid] = 0.f; }
    __syncthreads();

    int hw  = tid >> 5;   // 0..15 half-waves
    int l32 = tid & 31;
    unsigned i = start + hw;
    while (i + 48 < end) {
        uint2 P0 = payload[i];
        uint2 P1 = payload[i + 16];
        uint2 P2 = payload[i + 32];
        uint2 P3 = payload[i + 48];
        float tv0[4], tv1[4], tv2[4], tv3[4];
        const float* Tr0 = T_all + (size_t)(P0.y & 1023u) * D + l32;
        const float* Tr1 = T_all + (size_t)(P1.y & 1023u) * D + l32;
        const float* Tr2 = T_all + (size_t)(P2.y & 1023u) * D + l32;
        const float* Tr3 = T_all + (size_t)(P3.y & 1023u) * D + l32;
#pragma unroll
        for (int j = 0; j < 4; ++j) tv0[j] = Tr0[j * 32];
#pragma unroll
        for (int j = 0; j < 4; ++j) tv1[j] = Tr1[j * 32];
#pragma unroll
        for (int j = 0; j < 4; ++j) tv2[j] = Tr2[j * 32];
#pragma unroll
        for (int j = 0; j < 4; ++j) tv3[j] = Tr3[j * 32];
        float c0 = __uint_as_float(P0.x), c1 = __uint_as_float(P1.x);
        float c2 = __uint_as_float(P2.x), c3 = __uint_as_float(P3.x);
        float* A0 = acc + ((P0.y >> 10) & 127u) * D + l32;
        float* A1 = acc + ((P1.y >> 10) & 127u) * D + l32;
        float* A2 = acc + ((P2.y >> 10) & 127u) * D + l32;
        float* A3 = acc + ((P3.y >> 10) & 127u) * D + l32;
#pragma unroll
        for (int j = 0; j < 4; ++j) atomicAdd(&A0[j * 32], c0 * tv0[j]);
#pragma unroll
        for (int j = 0; j < 4; ++j) atomicAdd(&A1[j * 32], c1 * tv1[j]);
#pragma unroll
        for (int j = 0; j < 4; ++j) atomicAdd(&A2[j * 32], c2 * tv2[j]);
#pragma unroll
        for (int j = 0; j < 4; ++j) atomicAdd(&A3[j * 32], c3 * tv3[j]);
        i += 64;
    }
    for (; i < end; i += 16) {
        uint2 p = payload[i];
        float c = __uint_as_float(p.x);
        const float* Tr = T_all + (size_t)(p.y & 1023u) * D + l32;
        float* A = acc + ((p.y >> 10) & 127u) * D + l32;
#pragma unroll
        for (int j = 0; j < 4; ++j) atomicAdd(&A[j * 32], c * Tr[j * 32]);
    }
    __syncthreads();

    // epilogue: write tile + BN partials
    int q  = tid & 31;    // float4 column group
    int rl = tid >> 5;    // 0..15
    int valid = nent - row0; if (valid > RPB) valid = RPB;
    float4 s4 = make_float4(0.f, 0.f, 0.f, 0.f);
    float4 q4 = make_float4(0.f, 0.f, 0.f, 0.f);
    float4* out4 = (float4*)out;
    for (int r = rl; r < RPB; r += 16) {
        float4 v = ((float4*)(acc + r * D))[q];
        if (r < valid) {
            out4[(size_t)(row0 + r) * 32 + q] = v;
            s4.x += v.x; s4.y += v.y; s4.z += v.z; s4.w += v.w;
            q4.x += v.x * v.x; q4.y += v.y * v.y; q4.z += v.z * v.z; q4.w += v.w * v.w;
        }
    }
    atomicAdd(&ls[4 * q + 0], s4.x); atomicAdd(&ls[4 * q + 1], s4.y);
    atomicAdd(&ls[4 * q + 2], s4.z); atomicAdd(&ls[4 * q + 3], s4.w);
    atomicAdd(&lq[4 * q + 0], q4.x); atomicAdd(&lq[4 * q + 1], q4.y);
    atomicAdd(&lq[4 * q + 2], q4.z); atomicAdd(&lq[4 * q + 3], q4.w);
    __syncthreads();
    if (tid < D) {
        atomicAdd(&sums[tid], ls[tid]);
        atomicAdd(&sumsq[tid], lq[tid]);
    }
}

// ---------------- fallback (atomic) path kernels ----------------
__global__ __launch_bounds__(256) void degree_kernel(const int* __restrict__ rows, int E,
                                                     float* __restrict__ deg_in,
                                                     float* __restrict__ deg_out) {
    int total = 2 * E;
    int tid = blockIdx.x * blockDim.x + threadIdx.x;
    int nth = gridDim.x * blockDim.x;
    for (long b = (long)tid * BUNROLL; b < total; b += (long)nth * BUNROLL) {
        for (int k = 0; k < BUNROLL && b + k < total; ++k) {
            int r = rows[b + k];
            float* deg = (b + k < E) ? deg_in : deg_out;
            atomicAdd(&deg[r], 1.0f);
        }
    }
}

__global__ void scatter_kernel(const int* __restrict__ rows, const int* __restrict__ cols,
                               const int* __restrict__ etype,
                               const float* __restrict__ deg_in, const float* __restrict__ deg_out,
                               const float* __restrict__ T_in, const float* __restrict__ T_out,
                               float* __restrict__ out, int E) {
    int wave = (blockIdx.x * blockDim.x + threadIdx.x) >> 6;
    int lane = threadIdx.x & 63;
    int nwaves = (gridDim.x * blockDim.x) >> 6;
    int total = 2 * E;
    for (int e = wave; e < total; e += nwaves) {
        bool first = (e < E);
        int row = rows[e];
        int col = cols[e];
        int t = etype[e];
        const float* deg = first ? deg_in : deg_out;
        const float* T = first ? T_in : T_out;
        float dr = deg[row];
        float dc = deg[col];
        float norm = (dr > 0.f ? rsqrtf(dr) : 0.f) * (dc > 0.f ? rsqrtf(dc) : 0.f);
        float c = 0.5f * norm;
        if (c != 0.f) {
            float v0 = c * T[t * D + lane];
            float v1 = c * T[t * D + 64 + lane];
            long b = (long)row * D;
            atomicAdd(&out[b + lane], v0);
            atomicAdd(&out[b + 64 + lane], v1);
        }
    }
}

__global__ void bn_stats_kernel(const float* __restrict__ h, int nent,
                                float* __restrict__ sums, float* __restrict__ sumsq) {
    int col = threadIdx.x;
    float s = 0.f, s2 = 0.f;
    for (int r = blockIdx.x; r < nent; r += gridDim.x) {
        float v = h[(long)r * D + col];
        s += v;
        s2 += v * v;
    }
    atomicAdd(&sums[col], s);
    atomicAdd(&sumsq[col], s2);
}

// ---------------- BN apply (both paths) ----------------
__global__ void bn_apply_kernel(float* __restrict__ h,
                                const float* __restrict__ sums, const float* __restrict__ sumsq,
                                const float* __restrict__ gamma, const float* __restrict__ beta,
                                int nent) {
    long total = ((long)nent * D) / 4;
    long stride = (long)gridDim.x * blockDim.x;
    float inv_n = 1.0f / (float)nent;
    float4* h4 = (float4*)h;
    for (long i = (long)blockIdx.x * blockDim.x + threadIdx.x; i < total; i += stride) {
        int c0 = (int)((i * 4) & (D - 1));
        float4 v = h4[i];
        float r[4] = {v.x, v.y, v.z, v.w};
#pragma unroll
        for (int j = 0; j < 4; ++j) {
            int col = c0 + j;
            float mean = sums[col] * inv_n;
            float var = sumsq[col] * inv_n - mean * mean;
            float istd = rsqrtf(var + 1e-5f);
            r[j] = tanhf((r[j] - mean) * istd * gamma[col] + beta[col]);
        }
        h4[i] = make_float4(r[0], r[1], r[2], r[3]);
    }
}

extern "C" void kernel_launch(void* const* d_in, const int* in_sizes, int n_in,
                              void* d_out, int out_size, void* d_ws, size_t ws_size,
                              hipStream_t stream) {
    const float* rel_embed     = (const float*)d_in[0];
    const float* rel_embed_in  = (const float*)d_in[1];
    const float* rel_embed_out = (const float*)d_in[2];
    const float* w_in          = (const float*)d_in[3];
    const float* w_out         = (const float*)d_in[4];
    const float* bn_gamma      = (const float*)d_in[5];
    const float* bn_beta       = (const float*)d_in[6];
    const int*   edge_index    = (const int*)d_in[7];
    const int*   edge_type     = (const int*)d_in[8];

    const int nrel = in_sizes[0] / D;               // 500
    const int E2   = in_sizes[8];                   // 3,000,000
    const int E    = E2 / 2;                        // 1,500,000
    const int nent = (out_size - in_sizes[0]) / D;  // 200,000
    const int K    = (nent + RPB - 1) / RPB;        // 1563 buckets
    const int KG   = K * 8;                         // bucket*group counters
    const int ntiles = (KG + STILE - 1) / STILE;    // 13

    float* out = (float*)d_out;
    const int* rows = edge_index;
    const int* cols = edge_index + E2;

    // ---- workspace layout (fast path) ----
    // [deg_in | deg_out | cnt8 | sums | sumsq]  <- one memset
    // [cursor8 | base8 | tsum | toff | T_all | payload]
    float*        ws      = (float*)d_ws;
    float*        deg_in  = ws;                                    // nent
    float*        deg_out = deg_in + nent;                         // nent
    unsigned int* cnt8    = (unsigned int*)(deg_out + nent);       // KG
    float*        sums    = (float*)(cnt8 + KG);                   // D
    float*        sumsq   = sums + D;                              // D
    unsigned int* cursor8 = (unsigned int*)(sumsq + D);            // KG
    unsigned int* base8   = cursor8 + KG;                          // KG+1
    unsigned int* tsum    = base8 + KG + 1;                        // ntiles
    unsigned int* toff    = tsum + ntiles;                         // ntiles
    float*        T_all   = (float*)(toff + ntiles);               // 2*nrel*D
    uintptr_t pal = ((uintptr_t)(T_all + (size_t)2 * nrel * D) + 15) & ~(uintptr_t)15;
    uint2*        payload = (uint2*)pal;                           // E2
    size_t needed = (pal + (size_t)E2 * sizeof(uint2)) - (uintptr_t)d_ws;

    const int NB = (E2 + CHUNK - 1) / CHUNK;  // hist/scatter blocks (identical mapping)

    if (needed <= ws_size && ntiles <= 1024 && 2 * nrel <= 1024 && nent < (1 << 18)) {
        // ---------- fast bucketed path ----------
        hipMemsetAsync(deg_in, 0, ((size_t)2 * nent + KG + 2 * D) * sizeof(float), stream);

        transform2_kernel<<<2 * nrel, D, 0, stream>>>(rel_embed_in, w_in, rel_embed_out, w_out,
                                                      T_all, nrel);
        hist_degree_kernel<<<NB, 256, 0, stream>>>(rows, E, E2, deg_in, deg_out, cnt8);

        dinv_kernel<<<512, 256, 0, stream>>>(deg_in, 2 * nent);

        tile_sum_u32<<<ntiles, 256, 0, stream>>>(cnt8, tsum, KG);
        scan_tiles_kernel<<<1, 1024, 0, stream>>>(tsum, toff, base8, ntiles, KG);
        base_write_u32<<<ntiles, 256, 0, stream>>>(cnt8, toff, base8, KG);

        hipMemcpyAsync(cursor8, base8, (size_t)KG * sizeof(unsigned int),
                       hipMemcpyDeviceToDevice, stream);

        scatter2_kernel<<<NB, 256, 0, stream>>>(rows, cols, edge_type, deg_in, deg_out,
                                                cursor8, payload, E, E2, nrel);
        accum2_kernel<<<K, 512, 0, stream>>>(base8, payload, T_all, out, sums, sumsq, nent);
        bn_apply_kernel<<<4096, 256, 0, stream>>>(out, sums, sumsq, bn_gamma, bn_beta, nent);
    } else {
        // ---------- fallback atomic path ----------
        float* f_deg_in  = ws;
        float* f_deg_out = f_deg_in + nent;
        float* f_T_in    = f_deg_out + nent;
        float* f_T_out   = f_T_in + (size_t)nrel * D;
        float* f_sums    = f_T_out + (size_t)nrel * D;
        float* f_sumsq   = f_sums + D;

        hipMemsetAsync(out, 0, (size_t)nent * D * sizeof(float), stream);
        hipMemsetAsync(f_deg_in, 0, (size_t)2 * nent * sizeof(float), stream);
        hipMemsetAsync(f_sums, 0, (size_t)2 * D * sizeof(float), stream);

        transform2_kernel<<<2 * nrel, D, 0, stream>>>(rel_embed_in, w_in, rel_embed_out, w_out,
                                                      f_T_in, nrel);
        degree_kernel<<<1466, 256, 0, stream>>>(edge_index, E, f_deg_in, f_deg_out);
        scatter_kernel<<<2048, 256, 0, stream>>>(rows, cols, edge_type, f_deg_in, f_deg_out,
                                                 f_T_in, f_T_out, out, E);
        bn_stats_kernel<<<1024, D, 0, stream>>>(out, nent, f_sums, f_sumsq);
        bn_apply_kernel<<<4096, 256, 0, stream>>>(out, f_sums, f_sumsq, bn_gamma, bn_beta, nent);
    }

    hipMemcpyAsync(out + (size_t)nent * D, rel_embed,
                   (size_t)nrel * D * sizeof(float), hipMemcpyDeviceToDevice, stream);
}

// Round 7
// 635.653 us; speedup vs baseline: 4.3796x; 4.3796x over previous
//
#include <hip/hip_runtime.h>

#define D 128
#define BUNROLL 8
#define CHUNK (256 * BUNROLL)   // edges per block in hist/scatter (identical mapping!)
#define RPB 128                 // rows per bucket
#define CAP 6144                // max edges sorted in LDS per bucket (avg ~1920)

// ---------------- relation transform (both matrices in one launch) ----------------
__global__ void transform2_kernel(const float* __restrict__ Rin, const float* __restrict__ Win,
                                  const float* __restrict__ Rout, const float* __restrict__ Wout,
                                  float* __restrict__ T_all, int nrel) {
    __shared__ float row[D];
    int b = blockIdx.x;
    bool second = (b >= nrel);
    const float* R = second ? Rout : Rin;
    const float* W = second ? Wout : Win;
    int r = second ? b - nrel : b;
    int t = threadIdx.x;
    row[t] = R[r * D + t];
    __syncthreads();
    float acc = 0.f;
#pragma unroll 8
    for (int k = 0; k < D; ++k) acc += row[k] * W[k * D + t];
    T_all[(size_t)b * D + t] = acc;
}

// ---------------- fused degree + bucket histogram, XCD-local sub-counters ----------------
// deg8in/deg8out: u32 [g][row] (g-major: no cross-XCD line sharing)
// cnt8g: u32 [g][bucket]
__global__ __launch_bounds__(256) void hist3_kernel(
        const int* __restrict__ rows, int E, int E2,
        unsigned* __restrict__ deg8in, unsigned* __restrict__ deg8out,
        unsigned* __restrict__ cnt8g, int nent, int K) {
    int b = blockIdx.x;
    unsigned g = (unsigned)(b & 7);
    unsigned* din = deg8in + (size_t)g * nent;
    unsigned* dout = deg8out + (size_t)g * nent;
    unsigned* cb  = cnt8g + (size_t)g * K;
    long e0 = (long)b * CHUNK + threadIdx.x * BUNROLL;
    if (e0 + BUNROLL <= E2) {
        int r[BUNROLL];
#pragma unroll
        for (int k = 0; k < BUNROLL; ++k) r[k] = rows[e0 + k];
#pragma unroll
        for (int k = 0; k < BUNROLL; ++k) {
            atomicAdd(&((e0 + k < E) ? din : dout)[r[k]], 1u);
            atomicAdd(&cb[(unsigned)r[k] >> 7], 1u);
        }
    } else {
        for (int k = 0; e0 + k < E2; ++k) {
            int r = rows[e0 + k];
            atomicAdd(&((e0 + k < E) ? din : dout)[r], 1u);
            atomicAdd(&cb[(unsigned)r >> 7], 1u);
        }
    }
}

// sum 8 group counters -> dinv arrays
__global__ __launch_bounds__(256) void reduce3_kernel(
        const unsigned* __restrict__ deg8in, const unsigned* __restrict__ deg8out,
        float* __restrict__ dinv_in, float* __restrict__ dinv_out, int nent) {
    int r = blockIdx.x * blockDim.x + threadIdx.x;
    if (r >= nent) return;
    unsigned a = 0, b = 0;
#pragma unroll
    for (int g = 0; g < 8; ++g) {
        a += deg8in[(size_t)g * nent + r];
        b += deg8out[(size_t)g * nent + r];
    }
    dinv_in[r]  = a ? rsqrtf((float)a) : 0.f;
    dinv_out[r] = b ? rsqrtf((float)b) : 0.f;
}

// one-block exclusive scan over K8=K*8 counters, scan order p=bucket*8+g,
// gathering from cnt8g[g][bucket]; base[p], base[K8]=total
__global__ void scan3_kernel(const unsigned* __restrict__ cnt8g,
                             unsigned* __restrict__ base, int K8, int K) {
    const int T = 1024;
    int t = threadIdx.x;
    int chunk = (K8 + T - 1) / T;
    int s = t * chunk;
    int e = s + chunk; if (e > K8) e = K8;
    unsigned local = 0;
    for (int p = s; p < e; ++p) local += cnt8g[(size_t)(p & 7) * K + (p >> 3)];
    __shared__ unsigned ls[T];
    ls[t] = local;
    __syncthreads();
    for (int off = 1; off < T; off <<= 1) {
        unsigned add = (t >= off) ? ls[t - off] : 0u;
        __syncthreads();
        ls[t] += add;
        __syncthreads();
    }
    unsigned run = (t > 0) ? ls[t - 1] : 0u;
    for (int p = s; p < e; ++p) {
        base[p] = run;
        run += cnt8g[(size_t)(p & 7) * K + (p >> 3)];
    }
    if (t == T - 1) base[K8] = ls[T - 1];
}

// cursor8g[g][bucket] = base[bucket*8+g]  (cursor in XCD-local layout)
__global__ __launch_bounds__(256) void xcur_kernel(const unsigned* __restrict__ base,
                                                   unsigned* __restrict__ cursor8g,
                                                   int K8, int K) {
    int j = blockIdx.x * blockDim.x + threadIdx.x;
    if (j < K8) {
        int g = j / K;
        int bq = j - g * K;
        cursor8g[j] = base[bq * 8 + g];
    }
}

// ---------------- scatter into XCD-affine bucket regions ----------------
// payload = (coeff_f32, (row&127)<<10 | table_row)
__global__ __launch_bounds__(256) void scatter3_kernel(
        const int* __restrict__ rows, const int* __restrict__ cols,
        const int* __restrict__ etype,
        const float* __restrict__ dinv_in, const float* __restrict__ dinv_out,
        unsigned* __restrict__ cursor8g,
        uint2* __restrict__ payload, int E, int E2, int nrel, int K) {
    int b = blockIdx.x;
    unsigned g = (unsigned)(b & 7);
    unsigned* cur = cursor8g + (size_t)g * K;
    long e0 = (long)b * CHUNK + threadIdx.x * BUNROLL;
    if (e0 + BUNROLL <= E2) {
        int r[BUNROLL], c[BUNROLL], t[BUNROLL];
#pragma unroll
        for (int k = 0; k < BUNROLL; ++k) r[k] = rows[e0 + k];
#pragma unroll
        for (int k = 0; k < BUNROLL; ++k) c[k] = cols[e0 + k];
#pragma unroll
        for (int k = 0; k < BUNROLL; ++k) t[k] = etype[e0 + k];
        float cf[BUNROLL];
#pragma unroll
        for (int k = 0; k < BUNROLL; ++k) {
            const float* dv = (e0 + k < E) ? dinv_in : dinv_out;
            cf[k] = 0.5f * dv[r[k]] * dv[c[k]];
        }
#pragma unroll
        for (int k = 0; k < BUNROLL; ++k) {
            unsigned pos = atomicAdd(&cur[(unsigned)r[k] >> 7], 1u);
            unsigned ty = (unsigned)(t[k] + ((e0 + k < E) ? 0 : nrel));
            payload[pos] = make_uint2(__float_as_uint(cf[k]),
                                      (((unsigned)r[k] & 127u) << 10) | ty);
        }
    } else {
        for (int k = 0; e0 + k < E2; ++k) {
            long e = e0 + k;
            bool first = (e < E);
            const float* dv = first ? dinv_in : dinv_out;
            int r = rows[e];
            float cf = 0.5f * dv[r] * dv[cols[e]];
            unsigned pos = atomicAdd(&cur[(unsigned)r >> 7], 1u);
            payload[pos] = make_uint2(__float_as_uint(cf),
                                      (((unsigned)r & 127u) << 10) |
                                      (unsigned)(etype[e] + (first ? 0 : nrel)));
        }
    }
}

// ---------------- per-bucket sort + register accumulate + fused BN stats ----------------
__global__ __launch_bounds__(512) void accum3_kernel(
        const unsigned* __restrict__ base8t, const uint2* __restrict__ payload,
        const float* __restrict__ T_all, float* __restrict__ out,
        float* __restrict__ sums, float* __restrict__ sumsq, int nent) {
    __shared__ uint2 sp[CAP];              // 48 KB
    __shared__ unsigned hist[RPB];
    __shared__ unsigned hcur[RPB];
    __shared__ float ls[D], lq[D];
    int tid = threadIdx.x;
    int b = blockIdx.x;
    unsigned start = base8t[b * 8], end = base8t[b * 8 + 8];
    int n = (int)(end - start);
    int nin = n < CAP ? n : CAP;

    if (tid < RPB) { hist[tid] = 0; ls[tid] = 0.f; lq[tid] = 0.f; }
    __syncthreads();
    // pass 1: local-row histogram
    for (int i = tid; i < nin; i += 512)
        atomicAdd(&hist[(payload[start + i].y >> 10) & 127u], 1u);
    __syncthreads();
    // inclusive scan of hist[0..127]
    for (int off = 1; off < RPB; off <<= 1) {
        unsigned v = 0;
        if (tid < RPB && tid >= off) v = hist[tid - off];
        __syncthreads();
        if (tid < RPB) hist[tid] += v;
        __syncthreads();
    }
    if (tid < RPB) hcur[tid] = tid ? hist[tid - 1] : 0u;
    __syncthreads();
    // pass 2: reorder into LDS
    for (int i = tid; i < nin; i += 512) {
        uint2 p = payload[start + i];
        unsigned pos = atomicAdd(&hcur[(p.y >> 10) & 127u], 1u);
        sp[pos] = p;
    }
    __syncthreads();

    const float4* T4 = (const float4*)T_all;
    float4* out4 = (float4*)out;
    int hw = tid >> 5, l32 = tid & 31;
    int row0 = b << 7;
    float4 s4 = make_float4(0.f, 0.f, 0.f, 0.f);
    float4 q4 = make_float4(0.f, 0.f, 0.f, 0.f);
    for (int rr = 0; rr < 8; ++rr) {
        int r = (hw << 3) + rr;
        unsigned s0 = r ? hist[r - 1] : 0u;
        unsigned s1 = hist[r];
        float4 a = make_float4(0.f, 0.f, 0.f, 0.f);
        unsigned i = s0;
        for (; i + 4 <= s1; i += 4) {      // 4-deep independent chains
            uint2 p0 = sp[i], p1 = sp[i + 1], p2 = sp[i + 2], p3 = sp[i + 3];
            float4 t0 = T4[(size_t)(p0.y & 1023u) * 32 + l32];
            float4 t1 = T4[(size_t)(p1.y & 1023u) * 32 + l32];
            float4 t2 = T4[(size_t)(p2.y & 1023u) * 32 + l32];
            float4 t3 = T4[(size_t)(p3.y & 1023u) * 32 + l32];
            float c0 = __uint_as_float(p0.x), c1 = __uint_as_float(p1.x);
            float c2 = __uint_as_float(p2.x), c3 = __uint_as_float(p3.x);
            a.x += c0 * t0.x; a.y += c0 * t0.y; a.z += c0 * t0.z; a.w += c0 * t0.w;
            a.x += c1 * t1.x; a.y += c1 * t1.y; a.z += c1 * t1.z; a.w += c1 * t1.w;
            a.x += c2 * t2.x; a.y += c2 * t2.y; a.z += c2 * t2.z; a.w += c2 * t2.w;
            a.x += c3 * t3.x; a.y += c3 * t3.y; a.z += c3 * t3.z; a.w += c3 * t3.w;
        }
        for (; i < s1; ++i) {
            uint2 p = sp[i];
            float4 t = T4[(size_t)(p.y & 1023u) * 32 + l32];
            float c = __uint_as_float(p.x);
            a.x += c * t.x; a.y += c * t.y; a.z += c * t.z; a.w += c * t.w;
        }
        // overflow tail (n > CAP): scan remaining global payload (never hit at this scale)
        for (unsigned j = start + (unsigned)nin; j < end; ++j) {
            uint2 p = payload[j];
            if (((p.y >> 10) & 127u) == (unsigned)r) {
                float4 t = T4[(size_t)(p.y & 1023u) * 32 + l32];
                float c = __uint_as_float(p.x);
                a.x += c * t.x; a.y += c * t.y; a.z += c * t.z; a.w += c * t.w;
            }
        }
        int row = row0 + r;
        if (row < nent) {
            out4[(size_t)row * 32 + l32] = a;
            s4.x += a.x; s4.y += a.y; s4.z += a.z; s4.w += a.w;
            q4.x += a.x * a.x; q4.y += a.y * a.y; q4.z += a.z * a.z; q4.w += a.w * a.w;
        }
    }
    atomicAdd(&ls[4 * l32 + 0], s4.x); atomicAdd(&ls[4 * l32 + 1], s4.y);
    atomicAdd(&ls[4 * l32 + 2], s4.z); atomicAdd(&ls[4 * l32 + 3], s4.w);
    atomicAdd(&lq[4 * l32 + 0], q4.x); atomicAdd(&lq[4 * l32 + 1], q4.y);
    atomicAdd(&lq[4 * l32 + 2], q4.z); atomicAdd(&lq[4 * l32 + 3], q4.w);
    __syncthreads();
    if (tid < D) {
        atomicAdd(&sums[tid], ls[tid]);
        atomicAdd(&sumsq[tid], lq[tid]);
    }
}

// ---------------- fallback (atomic) path kernels ----------------
__global__ __launch_bounds__(256) void degree_kernel(const int* __restrict__ rows, int E,
                                                     float* __restrict__ deg_in,
                                                     float* __restrict__ deg_out) {
    int total = 2 * E;
    int tid = blockIdx.x * blockDim.x + threadIdx.x;
    int nth = gridDim.x * blockDim.x;
    for (long b = (long)tid * BUNROLL; b < total; b += (long)nth * BUNROLL) {
        for (int k = 0; k < BUNROLL && b + k < total; ++k) {
            int r = rows[b + k];
            float* deg = (b + k < E) ? deg_in : deg_out;
            atomicAdd(&deg[r], 1.0f);
        }
    }
}

__global__ void scatter_kernel(const int* __restrict__ rows, const int* __restrict__ cols,
                               const int* __restrict__ etype,
                               const float* __restrict__ deg_in, const float* __restrict__ deg_out,
                               const float* __restrict__ T_in, const float* __restrict__ T_out,
                               float* __restrict__ out, int E) {
    int wave = (blockIdx.x * blockDim.x + threadIdx.x) >> 6;
    int lane = threadIdx.x & 63;
    int nwaves = (gridDim.x * blockDim.x) >> 6;
    int total = 2 * E;
    for (int e = wave; e < total; e += nwaves) {
        bool first = (e < E);
        int row = rows[e];
        int col = cols[e];
        int t = etype[e];
        const float* deg = first ? deg_in : deg_out;
        const float* T = first ? T_in : T_out;
        float dr = deg[row];
        float dc = deg[col];
        float norm = (dr > 0.f ? rsqrtf(dr) : 0.f) * (dc > 0.f ? rsqrtf(dc) : 0.f);
        float c = 0.5f * norm;
        if (c != 0.f) {
            float v0 = c * T[t * D + lane];
            float v1 = c * T[t * D + 64 + lane];
            long b = (long)row * D;
            atomicAdd(&out[b + lane], v0);
            atomicAdd(&out[b + 64 + lane], v1);
        }
    }
}

__global__ void bn_stats_kernel(const float* __restrict__ h, int nent,
                                float* __restrict__ sums, float* __restrict__ sumsq) {
    int col = threadIdx.x;
    float s = 0.f, s2 = 0.f;
    for (int r = blockIdx.x; r < nent; r += gridDim.x) {
        float v = h[(long)r * D + col];
        s += v;
        s2 += v * v;
    }
    atomicAdd(&sums[col], s);
    atomicAdd(&sumsq[col], s2);
}

// ---------------- BN apply (both paths) ----------------
__global__ void bn_apply_kernel(float* __restrict__ h,
                                const float* __restrict__ sums, const float* __restrict__ sumsq,
                                const float* __restrict__ gamma, const float* __restrict__ beta,
                                int nent) {
    long total = ((long)nent * D) / 4;
    long stride = (long)gridDim.x * blockDim.x;
    float inv_n = 1.0f / (float)nent;
    float4* h4 = (float4*)h;
    for (long i = (long)blockIdx.x * blockDim.x + threadIdx.x; i < total; i += stride) {
        int c0 = (int)((i * 4) & (D - 1));
        float4 v = h4[i];
        float r[4] = {v.x, v.y, v.z, v.w};
#pragma unroll
        for (int j = 0; j < 4; ++j) {
            int col = c0 + j;
            float mean = sums[col] * inv_n;
            float var = sumsq[col] * inv_n - mean * mean;
            float istd = rsqrtf(var + 1e-5f);
            r[j] = tanhf((r[j] - mean) * istd * gamma[col] + beta[col]);
        }
        h4[i] = make_float4(r[0], r[1], r[2], r[3]);
    }
}

extern "C" void kernel_launch(void* const* d_in, const int* in_sizes, int n_in,
                              void* d_out, int out_size, void* d_ws, size_t ws_size,
                              hipStream_t stream) {
    const float* rel_embed     = (const float*)d_in[0];
    const float* rel_embed_in  = (const float*)d_in[1];
    const float* rel_embed_out = (const float*)d_in[2];
    const float* w_in          = (const float*)d_in[3];
    const float* w_out         = (const float*)d_in[4];
    const float* bn_gamma      = (const float*)d_in[5];
    const float* bn_beta       = (const float*)d_in[6];
    const int*   edge_index    = (const int*)d_in[7];
    const int*   edge_type     = (const int*)d_in[8];

    const int nrel = in_sizes[0] / D;               // 500
    const int E2   = in_sizes[8];                   // 3,000,000
    const int E    = E2 / 2;                        // 1,500,000
    const int nent = (out_size - in_sizes[0]) / D;  // 200,000
    const int K    = (nent + RPB - 1) / RPB;        // 1563 buckets
    const int K8   = K * 8;

    float* out = (float*)d_out;
    const int* rows = edge_index;
    const int* cols = edge_index + E2;

    // ---- workspace layout (fast path) ----
    float*        ws       = (float*)d_ws;
    float*        dinv_in  = ws;                                  // nent
    float*        dinv_out = dinv_in + nent;                      // nent
    float*        sums     = dinv_out + nent;                     // D
    float*        sumsq    = sums + D;                            // D
    unsigned*     cnt8g    = (unsigned*)(sumsq + D);              // K8
    unsigned*     base8t   = cnt8g + K8;                          // K8+1
    unsigned*     cursor8g = base8t + K8 + 1;                     // K8
    float*        T_all    = (float*)(cursor8g + K8);             // 2*nrel*D
    uintptr_t pal = ((uintptr_t)(T_all + (size_t)2 * nrel * D) + 15) & ~(uintptr_t)15;
    uint2*        payload  = (uint2*)pal;                         // E2
    // deg8 sub-counters aliased into the payload region (consumed before scatter)
    unsigned*     deg8in   = (unsigned*)payload;                  // 8*nent
    unsigned*     deg8out  = deg8in + (size_t)8 * nent;           // 8*nent
    size_t needed = (pal + (size_t)E2 * sizeof(uint2)) - (uintptr_t)d_ws;

    const int NB = (E2 + CHUNK - 1) / CHUNK;

    bool fast = (needed <= ws_size) && (2 * nrel <= 1024) &&
                ((size_t)16 * nent * 4 <= (size_t)E2 * 8) && (K8 <= 16384);

    if (fast) {
        hipMemsetAsync(deg8in, 0, (size_t)16 * nent * sizeof(unsigned), stream);
        hipMemsetAsync(cnt8g, 0, (size_t)K8 * sizeof(unsigned), stream);
        hipMemsetAsync(sums, 0, (size_t)2 * D * sizeof(float), stream);

        transform2_kernel<<<2 * nrel, D, 0, stream>>>(rel_embed_in, w_in, rel_embed_out, w_out,
                                                      T_all, nrel);
        hist3_kernel<<<NB, 256, 0, stream>>>(rows, E, E2, deg8in, deg8out, cnt8g, nent, K);
        reduce3_kernel<<<(nent + 255) / 256, 256, 0, stream>>>(deg8in, deg8out,
                                                               dinv_in, dinv_out, nent);
        scan3_kernel<<<1, 1024, 0, stream>>>(cnt8g, base8t, K8, K);
        xcur_kernel<<<(K8 + 255) / 256, 256, 0, stream>>>(base8t, cursor8g, K8, K);
        scatter3_kernel<<<NB, 256, 0, stream>>>(rows, cols, edge_type, dinv_in, dinv_out,
                                                cursor8g, payload, E, E2, nrel, K);
        accum3_kernel<<<K, 512, 0, stream>>>(base8t, payload, T_all, out, sums, sumsq, nent);
        bn_apply_kernel<<<4096, 256, 0, stream>>>(out, sums, sumsq, bn_gamma, bn_beta, nent);
    } else {
        // ---------- fallback atomic path ----------
        float* f_deg_in  = ws;
        float* f_deg_out = f_deg_in + nent;
        float* f_T_in    = f_deg_out + nent;
        float* f_T_out   = f_T_in + (size_t)nrel * D;
        float* f_sums    = f_T_out + (size_t)nrel * D;
        float* f_sumsq   = f_sums + D;

        hipMemsetAsync(out, 0, (size_t)nent * D * sizeof(float), stream);
        hipMemsetAsync(f_deg_in, 0, (size_t)2 * nent * sizeof(float), stream);
        hipMemsetAsync(f_sums, 0, (size_t)2 * D * sizeof(float), stream);

        transform2_kernel<<<2 * nrel, D, 0, stream>>>(rel_embed_in, w_in, rel_embed_out, w_out,
                                                      f_T_in, nrel);
        degree_kernel<<<1466, 256, 0, stream>>>(edge_index, E, f_deg_in, f_deg_out);
        scatter_kernel<<<2048, 256, 0, stream>>>(rows, cols, edge_type, f_deg_in, f_deg_out,
                                                 f_T_in, f_T_out, out, E);
        bn_stats_kernel<<<1024, D, 0, stream>>>(out, nent, f_sums, f_sumsq);
        bn_apply_kernel<<<4096, 256, 0, stream>>>(out, f_sums, f_sumsq, bn_gamma, bn_beta, nent);
    }

    hipMemcpyAsync(out + (size_t)nent * D, rel_embed,
                   (size_t)nrel * D * sizeof(float), hipMemcpyDeviceToDevice, stream);
}

// Round 8
// 302.195 us; speedup vs baseline: 9.2122x; 2.1035x over previous
//
#include <hip/hip_runtime.h>

#define D 128
#define BUNROLL 8
#define RPB 128                 // rows per bucket
#define CAP 6144                // max edges sorted in LDS per bucket (avg ~1920)
#define MAXK 2048               // max buckets (LDS histogram size)
#define CHUNK4 16384            // edges per block in hist4/scatter4 (identical mapping!)
#define STILE 1024              // scan tile

// ---------------- relation transform (both matrices in one launch) ----------------
__global__ void transform2_kernel(const float* __restrict__ Rin, const float* __restrict__ Win,
                                  const float* __restrict__ Rout, const float* __restrict__ Wout,
                                  float* __restrict__ T_all, int nrel) {
    __shared__ float row[D];
    int b = blockIdx.x;
    bool second = (b >= nrel);
    const float* R = second ? Rout : Rin;
    const float* W = second ? Wout : Win;
    int r = second ? b - nrel : b;
    int t = threadIdx.x;
    row[t] = R[r * D + t];
    __syncthreads();
    float acc = 0.f;
#pragma unroll 8
    for (int k = 0; k < D; ++k) acc += row[k] * W[k * D + t];
    T_all[(size_t)b * D + t] = acc;
}

// ---------------- pass 1: per-block LDS bucket histogram (NO global atomics) ----------------
// cnt[bucket * NB + blk] = #edges of this block in bucket
__global__ __launch_bounds__(512) void hist4_kernel(
        const int* __restrict__ rows, int E2,
        unsigned* __restrict__ cnt, int NB, int K) {
    __shared__ unsigned h[MAXK];
    int tid = threadIdx.x, blk = blockIdx.x;
    for (int i = tid; i < K; i += 512) h[i] = 0;
    __syncthreads();
    long s = (long)blk * CHUNK4;
    long e = s + CHUNK4; if (e > E2) e = E2;
    for (long i = s + tid; i < e; i += 512)
        atomicAdd(&h[((unsigned)rows[i]) >> 7], 1u);
    __syncthreads();
    for (int i = tid; i < K; i += 512)
        cnt[(size_t)i * NB + blk] = h[i];
}

// ---------------- device-wide scan over n=NB*K counters (3 kernels, in-place alias ok) ----
__global__ __launch_bounds__(256) void tile_sum_u32(const unsigned int* __restrict__ cnt,
                                                    unsigned int* __restrict__ tsum, int n) {
    int tid = threadIdx.x;
    int i0 = blockIdx.x * STILE + tid * 4;
    unsigned int s = 0;
#pragma unroll
    for (int k = 0; k < 4; ++k) {
        int i = i0 + k;
        if (i < n) s += cnt[i];
    }
    __shared__ unsigned int ls[256];
    ls[tid] = s;
    __syncthreads();
    for (int off = 128; off >= 1; off >>= 1) {
        if (tid < off) ls[tid] += ls[tid + off];
        __syncthreads();
    }
    if (tid == 0) tsum[blockIdx.x] = ls[0];
}

__global__ void scan_tiles_kernel(const unsigned int* __restrict__ tile_sums,
                                  unsigned int* __restrict__ tile_off,
                                  unsigned int* __restrict__ base, int ntiles, int n) {
    int t = threadIdx.x; // blockDim = 1024
    __shared__ unsigned int ls[1024];
    unsigned int v = (t < ntiles) ? tile_sums[t] : 0u;
    ls[t] = v;
    __syncthreads();
    for (int off = 1; off < 1024; off <<= 1) {
        unsigned int add = (t >= off) ? ls[t - off] : 0u;
        __syncthreads();
        ls[t] += add;
        __syncthreads();
    }
    if (t < ntiles) tile_off[t] = ls[t] - v; // exclusive
    if (t == 1023) base[n] = ls[1023];       // grand total
}

// in-place safe when base==cnt: each element read before written by its own thread
__global__ __launch_bounds__(256) void base_write_u32(const unsigned int* __restrict__ cnt,
                                                      const unsigned int* __restrict__ tile_off,
                                                      unsigned int* __restrict__ base, int n) {
    int tid = threadIdx.x;
    int i0 = blockIdx.x * STILE + tid * 4;
    unsigned int c[4];
#pragma unroll
    for (int k = 0; k < 4; ++k) {
        int i = i0 + k;
        c[k] = (i < n) ? cnt[i] : 0u;
    }
    unsigned int s = c[0] + c[1] + c[2] + c[3];
    __shared__ unsigned int ls[256];
    ls[tid] = s;
    __syncthreads();
    for (int off = 1; off < 256; off <<= 1) {
        unsigned int add = (tid >= off) ? ls[tid - off] : 0u;
        __syncthreads();
        ls[tid] += add;
        __syncthreads();
    }
    unsigned int run = (tid > 0 ? ls[tid - 1] : 0u) + tile_off[blockIdx.x];
#pragma unroll
    for (int k = 0; k < 4; ++k) {
        int i = i0 + k;
        if (i < n) base[i] = run;
        run += c[k];
    }
}

// ---------------- pass 2: scatter with LDS ranks (NO global atomics) ----------------
// payload = (col, (row&127)<<10 | type)   -- coeff deferred to accum
__global__ __launch_bounds__(512) void scatter4_kernel(
        const int* __restrict__ rows, const int* __restrict__ cols,
        const int* __restrict__ etype, const unsigned* __restrict__ base,
        uint2* __restrict__ payload, int E, int E2, int nrel, int NB, int K) {
    __shared__ unsigned cur[MAXK];
    int tid = threadIdx.x, blk = blockIdx.x;
    for (int i = tid; i < K; i += 512) cur[i] = base[(size_t)i * NB + blk];
    __syncthreads();
    long s = (long)blk * CHUNK4;
    long e = s + CHUNK4; if (e > E2) e = E2;
    for (long i = s + tid; i < e; i += 512) {
        unsigned r = (unsigned)rows[i];
        unsigned c = (unsigned)cols[i];
        unsigned t = (unsigned)etype[i];
        unsigned ty = t + ((i < E) ? 0u : (unsigned)nrel);
        unsigned pos = atomicAdd(&cur[r >> 7], 1u);   // LDS atomic
        payload[pos] = make_uint2(c, ((r & 127u) << 10) | ty);
    }
}

// ---------------- degrees from sorted payload (NO global atomics) ----------------
// dinvAll[0..nent) = deg_in^-1/2 ; dinvAll[nent..2nent) = deg_out^-1/2
__global__ __launch_bounds__(512) void degsort_kernel(
        const unsigned* __restrict__ base, const uint2* __restrict__ payload,
        float* __restrict__ dinvAll, int nent, int nrel, int NB, int K) {
    __shared__ unsigned h2[RPB * 2];
    int tid = threadIdx.x, b = blockIdx.x;
    for (int i = tid; i < RPB * 2; i += 512) h2[i] = 0;
    __syncthreads();
    size_t NBK = (size_t)NB * K;
    unsigned s = base[(size_t)b * NB];
    unsigned e = (b + 1 < K) ? base[(size_t)(b + 1) * NB] : base[NBK];
    for (unsigned i = s + tid; i < e; i += 512) {
        unsigned y = payload[i].y;
        unsigned lr = (y >> 10) & 127u;
        unsigned fo = ((y & 1023u) >= (unsigned)nrel) ? 1u : 0u;
        atomicAdd(&h2[lr * 2 + fo], 1u);
    }
    __syncthreads();
    if (tid < RPB) {
        int row = (b << 7) + tid;
        if (row < nent) {
            unsigned a = h2[tid * 2], o = h2[tid * 2 + 1];
            dinvAll[row]        = a ? rsqrtf((float)a) : 0.f;
            dinvAll[nent + row] = o ? rsqrtf((float)o) : 0.f;
        }
    }
}

// ---------------- per-bucket LDS sort + register accumulate + fused BN stats ----------------
__global__ __launch_bounds__(512) void accum4_kernel(
        const unsigned* __restrict__ base, const uint2* __restrict__ payload,
        const float* __restrict__ T_all, const float* __restrict__ dinvAll,
        float* __restrict__ out, float* __restrict__ sums, float* __restrict__ sumsq,
        int nent, int nrel, int NB, int K) {
    __shared__ uint2 sp[CAP];              // 48 KB
    __shared__ unsigned hist[RPB];
    __shared__ unsigned hcur[RPB];
    __shared__ float ls[D], lq[D];
    int tid = threadIdx.x;
    int b = blockIdx.x;
    size_t NBK = (size_t)NB * K;
    unsigned start = base[(size_t)b * NB];
    unsigned end   = (b + 1 < K) ? base[(size_t)(b + 1) * NB] : base[NBK];
    int n = (int)(end - start);
    int nin = n < CAP ? n : CAP;

    if (tid < RPB) { hist[tid] = 0; ls[tid] = 0.f; lq[tid] = 0.f; }
    __syncthreads();
    for (int i = tid; i < nin; i += 512)
        atomicAdd(&hist[(payload[start + i].y >> 10) & 127u], 1u);
    __syncthreads();
    for (int off = 1; off < RPB; off <<= 1) {
        unsigned v = 0;
        if (tid < RPB && tid >= off) v = hist[tid - off];
        __syncthreads();
        if (tid < RPB) hist[tid] += v;
        __syncthreads();
    }
    if (tid < RPB) hcur[tid] = tid ? hist[tid - 1] : 0u;
    __syncthreads();
    for (int i = tid; i < nin; i += 512) {
        uint2 p = payload[start + i];
        unsigned pos = atomicAdd(&hcur[(p.y >> 10) & 127u], 1u);
        sp[pos] = p;
    }
    __syncthreads();

    const float4* T4 = (const float4*)T_all;
    float4* out4 = (float4*)out;
    int hw = tid >> 5, l32 = tid & 31;
    int row0 = b << 7;
    unsigned unrel = (unsigned)nrel;
    float4 s4 = make_float4(0.f, 0.f, 0.f, 0.f);
    float4 q4 = make_float4(0.f, 0.f, 0.f, 0.f);
    for (int rr = 0; rr < 8; ++rr) {
        int r = (hw << 3) + rr;
        int row = row0 + r;
        float da_in = 0.f, da_out = 0.f;
        if (row < nent) { da_in = dinvAll[row]; da_out = dinvAll[nent + row]; }
        unsigned s0 = r ? hist[r - 1] : 0u;
        unsigned s1 = hist[r];
        float4 a = make_float4(0.f, 0.f, 0.f, 0.f);
        unsigned i = s0;
        for (; i + 4 <= s1; i += 4) {      // 4-deep independent chains
            uint2 p0 = sp[i], p1 = sp[i + 1], p2 = sp[i + 2], p3 = sp[i + 3];
            unsigned ty0 = p0.y & 1023u, ty1 = p1.y & 1023u;
            unsigned ty2 = p2.y & 1023u, ty3 = p3.y & 1023u;
            bool f0 = ty0 < unrel, f1 = ty1 < unrel, f2 = ty2 < unrel, f3 = ty3 < unrel;
            float dc0 = dinvAll[(f0 ? 0 : nent) + p0.x];
            float dc1 = dinvAll[(f1 ? 0 : nent) + p1.x];
            float dc2 = dinvAll[(f2 ? 0 : nent) + p2.x];
            float dc3 = dinvAll[(f3 ? 0 : nent) + p3.x];
            float4 t0 = T4[(size_t)ty0 * 32 + l32];
            float4 t1 = T4[(size_t)ty1 * 32 + l32];
            float4 t2 = T4[(size_t)ty2 * 32 + l32];
            float4 t3 = T4[(size_t)ty3 * 32 + l32];
            float c0 = 0.5f * (f0 ? da_in : da_out) * dc0;
            float c1 = 0.5f * (f1 ? da_in : da_out) * dc1;
            float c2 = 0.5f * (f2 ? da_in : da_out) * dc2;
            float c3 = 0.5f * (f3 ? da_in : da_out) * dc3;
            a.x += c0 * t0.x; a.y += c0 * t0.y; a.z += c0 * t0.z; a.w += c0 * t0.w;
            a.x += c1 * t1.x; a.y += c1 * t1.y; a.z += c1 * t1.z; a.w += c1 * t1.w;
            a.x += c2 * t2.x; a.y += c2 * t2.y; a.z += c2 * t2.z; a.w += c2 * t2.w;
            a.x += c3 * t3.x; a.y += c3 * t3.y; a.z += c3 * t3.z; a.w += c3 * t3.w;
        }
        for (; i < s1; ++i) {
            uint2 p = sp[i];
            unsigned ty = p.y & 1023u;
            bool f = ty < unrel;
            float c = 0.5f * (f ? da_in : da_out) * dinvAll[(f ? 0 : nent) + p.x];
            float4 t = T4[(size_t)ty * 32 + l32];
            a.x += c * t.x; a.y += c * t.y; a.z += c * t.z; a.w += c * t.w;
        }
        // overflow tail (n > CAP): scan remaining global payload (never hit at this scale)
        for (unsigned j = start + (unsigned)nin; j < end; ++j) {
            uint2 p = payload[j];
            if (((p.y >> 10) & 127u) == (unsigned)r) {
                unsigned ty = p.y & 1023u;
                bool f = ty < unrel;
                float c = 0.5f * (f ? da_in : da_out) * dinvAll[(f ? 0 : nent) + p.x];
                float4 t = T4[(size_t)ty * 32 + l32];
                a.x += c * t.x; a.y += c * t.y; a.z += c * t.z; a.w += c * t.w;
            }
        }
        if (row < nent) {
            out4[(size_t)row * 32 + l32] = a;
            s4.x += a.x; s4.y += a.y; s4.z += a.z; s4.w += a.w;
            q4.x += a.x * a.x; q4.y += a.y * a.y; q4.z += a.z * a.z; q4.w += a.w * a.w;
        }
    }
    atomicAdd(&ls[4 * l32 + 0], s4.x); atomicAdd(&ls[4 * l32 + 1], s4.y);
    atomicAdd(&ls[4 * l32 + 2], s4.z); atomicAdd(&ls[4 * l32 + 3], s4.w);
    atomicAdd(&lq[4 * l32 + 0], q4.x); atomicAdd(&lq[4 * l32 + 1], q4.y);
    atomicAdd(&lq[4 * l32 + 2], q4.z); atomicAdd(&lq[4 * l32 + 3], q4.w);
    __syncthreads();
    if (tid < D) {
        atomicAdd(&sums[tid], ls[tid]);
        atomicAdd(&sumsq[tid], lq[tid]);
    }
}

// ---------------- fallback (atomic) path kernels ----------------
__global__ __launch_bounds__(256) void degree_kernel(const int* __restrict__ rows, int E,
                                                     float* __restrict__ deg_in,
                                                     float* __restrict__ deg_out) {
    int total = 2 * E;
    int tid = blockIdx.x * blockDim.x + threadIdx.x;
    int nth = gridDim.x * blockDim.x;
    for (long b = (long)tid * BUNROLL; b < total; b += (long)nth * BUNROLL) {
        for (int k = 0; k < BUNROLL && b + k < total; ++k) {
            int r = rows[b + k];
            float* deg = (b + k < E) ? deg_in : deg_out;
            atomicAdd(&deg[r], 1.0f);
        }
    }
}

__global__ void scatter_kernel(const int* __restrict__ rows, const int* __restrict__ cols,
                               const int* __restrict__ etype,
                               const float* __restrict__ deg_in, const float* __restrict__ deg_out,
                               const float* __restrict__ T_in, const float* __restrict__ T_out,
                               float* __restrict__ out, int E) {
    int wave = (blockIdx.x * blockDim.x + threadIdx.x) >> 6;
    int lane = threadIdx.x & 63;
    int nwaves = (gridDim.x * blockDim.x) >> 6;
    int total = 2 * E;
    for (int e = wave; e < total; e += nwaves) {
        bool first = (e < E);
        int row = rows[e];
        int col = cols[e];
        int t = etype[e];
        const float* deg = first ? deg_in : deg_out;
        const float* T = first ? T_in : T_out;
        float dr = deg[row];
        float dc = deg[col];
        float norm = (dr > 0.f ? rsqrtf(dr) : 0.f) * (dc > 0.f ? rsqrtf(dc) : 0.f);
        float c = 0.5f * norm;
        if (c != 0.f) {
            float v0 = c * T[t * D + lane];
            float v1 = c * T[t * D + 64 + lane];
            long b = (long)row * D;
            atomicAdd(&out[b + lane], v0);
            atomicAdd(&out[b + 64 + lane], v1);
        }
    }
}

__global__ void bn_stats_kernel(const float* __restrict__ h, int nent,
                                float* __restrict__ sums, float* __restrict__ sumsq) {
    int col = threadIdx.x;
    float s = 0.f, s2 = 0.f;
    for (int r = blockIdx.x; r < nent; r += gridDim.x) {
        float v = h[(long)r * D + col];
        s += v;
        s2 += v * v;
    }
    atomicAdd(&sums[col], s);
    atomicAdd(&sumsq[col], s2);
}

// ---------------- BN apply (both paths) ----------------
__global__ void bn_apply_kernel(float* __restrict__ h,
                                const float* __restrict__ sums, const float* __restrict__ sumsq,
                                const float* __restrict__ gamma, const float* __restrict__ beta,
                                int nent) {
    long total = ((long)nent * D) / 4;
    long stride = (long)gridDim.x * blockDim.x;
    float inv_n = 1.0f / (float)nent;
    float4* h4 = (float4*)h;
    for (long i = (long)blockIdx.x * blockDim.x + threadIdx.x; i < total; i += stride) {
        int c0 = (int)((i * 4) & (D - 1));
        float4 v = h4[i];
        float r[4] = {v.x, v.y, v.z, v.w};
#pragma unroll
        for (int j = 0; j < 4; ++j) {
            int col = c0 + j;
            float mean = sums[col] * inv_n;
            float var = sumsq[col] * inv_n - mean * mean;
            float istd = rsqrtf(var + 1e-5f);
            r[j] = tanhf((r[j] - mean) * istd * gamma[col] + beta[col]);
        }
        h4[i] = make_float4(r[0], r[1], r[2], r[3]);
    }
}

extern "C" void kernel_launch(void* const* d_in, const int* in_sizes, int n_in,
                              void* d_out, int out_size, void* d_ws, size_t ws_size,
                              hipStream_t stream) {
    const float* rel_embed     = (const float*)d_in[0];
    const float* rel_embed_in  = (const float*)d_in[1];
    const float* rel_embed_out = (const float*)d_in[2];
    const float* w_in          = (const float*)d_in[3];
    const float* w_out         = (const float*)d_in[4];
    const float* bn_gamma      = (const float*)d_in[5];
    const float* bn_beta       = (const float*)d_in[6];
    const int*   edge_index    = (const int*)d_in[7];
    const int*   edge_type     = (const int*)d_in[8];

    const int nrel = in_sizes[0] / D;               // 500
    const int E2   = in_sizes[8];                   // 3,000,000
    const int E    = E2 / 2;                        // 1,500,000
    const int nent = (out_size - in_sizes[0]) / D;  // 200,000
    const int K    = (nent + RPB - 1) / RPB;        // 1563 buckets
    const int NB   = (E2 + CHUNK4 - 1) / CHUNK4;    // 184 blocks
    const long NBK = (long)NB * K;                  // 287,592 counters
    const int ntiles = (int)((NBK + STILE - 1) / STILE);  // 281

    float* out = (float*)d_out;
    const int* rows = edge_index;
    const int* cols = edge_index + E2;

    // ---- workspace layout (fast path) ----
    float*    ws       = (float*)d_ws;
    float*    dinvAll  = ws;                                   // 2*nent
    float*    sums     = dinvAll + (size_t)2 * nent;           // D
    float*    sumsq    = sums + D;                             // D
    unsigned* cnt      = (unsigned*)(sumsq + D);               // NBK+1 (scan in place)
    unsigned* tsum     = cnt + NBK + 1;                        // ntiles
    unsigned* toff     = tsum + ntiles;                        // ntiles
    float*    T_all    = (float*)(toff + ntiles);              // 2*nrel*D
    uintptr_t pal = ((uintptr_t)(T_all + (size_t)2 * nrel * D) + 15) & ~(uintptr_t)15;
    uint2*    payload  = (uint2*)pal;                          // E2
    size_t needed = (pal + (size_t)E2 * sizeof(uint2)) - (uintptr_t)d_ws;

    bool fast = (needed <= ws_size) && (K <= MAXK) && (2 * nrel <= 1024) &&
                (ntiles <= 1024);

    if (fast) {
        hipMemsetAsync(sums, 0, (size_t)2 * D * sizeof(float), stream);

        transform2_kernel<<<2 * nrel, D, 0, stream>>>(rel_embed_in, w_in, rel_embed_out, w_out,
                                                      T_all, nrel);
        hist4_kernel<<<NB, 512, 0, stream>>>(rows, E2, cnt, NB, K);
        tile_sum_u32<<<ntiles, 256, 0, stream>>>(cnt, tsum, (int)NBK);
        scan_tiles_kernel<<<1, 1024, 0, stream>>>(tsum, toff, cnt, ntiles, (int)NBK);
        base_write_u32<<<ntiles, 256, 0, stream>>>(cnt, toff, cnt, (int)NBK);
        scatter4_kernel<<<NB, 512, 0, stream>>>(rows, cols, edge_type, cnt,
                                                payload, E, E2, nrel, NB, K);
        degsort_kernel<<<K, 512, 0, stream>>>(cnt, payload, dinvAll, nent, nrel, NB, K);
        accum4_kernel<<<K, 512, 0, stream>>>(cnt, payload, T_all, dinvAll,
                                             out, sums, sumsq, nent, nrel, NB, K);
        bn_apply_kernel<<<4096, 256, 0, stream>>>(out, sums, sumsq, bn_gamma, bn_beta, nent);
    } else {
        // ---------- fallback atomic path ----------
        float* f_deg_in  = ws;
        float* f_deg_out = f_deg_in + nent;
        float* f_T_in    = f_deg_out + nent;
        float* f_T_out   = f_T_in + (size_t)nrel * D;
        float* f_sums    = f_T_out + (size_t)nrel * D;
        float* f_sumsq   = f_sums + D;

        hipMemsetAsync(out, 0, (size_t)nent * D * sizeof(float), stream);
        hipMemsetAsync(f_deg_in, 0, (size_t)2 * nent * sizeof(float), stream);
        hipMemsetAsync(f_sums, 0, (size_t)2 * D * sizeof(float), stream);

        transform2_kernel<<<2 * nrel, D, 0, stream>>>(rel_embed_in, w_in, rel_embed_out, w_out,
                                                      f_T_in, nrel);
        degree_kernel<<<1466, 256, 0, stream>>>(edge_index, E, f_deg_in, f_deg_out);
        scatter_kernel<<<2048, 256, 0, stream>>>(rows, cols, edge_type, f_deg_in, f_deg_out,
                                                 f_T_in, f_T_out, out, E);
        bn_stats_kernel<<<1024, D, 0, stream>>>(out, nent, f_sums, f_sumsq);
        bn_apply_kernel<<<4096, 256, 0, stream>>>(out, f_sums, f_sumsq, bn_gamma, bn_beta, nent);
    }

    hipMemcpyAsync(out + (size_t)nent * D, rel_embed,
                   (size_t)nrel * D * sizeof(float), hipMemcpyDeviceToDevice, stream);
}